// Round 2
// baseline (61.452 us; speedup 1.0000x reference)
//
#include <hip/hip_runtime.h>
#include <math.h>

#define BWALK 4096
#define NS 64
#define DD 256
#define NE 16

__global__ __launch_bounds__(256) void outputheaddet_kernel(
    const float* __restrict__ y,
    const float* __restrict__ Mup,
    const float* __restrict__ Mdn,
    const int* __restrict__ R,
    float* __restrict__ out,
    int mode)   // 0: interleaved (re,im) pairs; 1: real (logabsdet) only
{
    const int b = blockIdx.x;
    const int tid = threadIdx.x;

    __shared__ int   sR[NE];
    __shared__ float sY[NE][DD];      // 16 KB: the 16 gathered y rows
    __shared__ float sA[NE][NE + 1];  // 16x16 A, padded row stride

    if (tid < NE) sR[tid] = R[b * NE + tid];
    __syncthreads();

    // ---- stage the 16 needed y rows into LDS (float4 loads) ----
    {
        const int i  = tid >> 4;          // gathered-row index 0..15
        const int d0 = (tid & 15) * 16;   // 16 floats per thread
        const int n    = sR[i];
        const int slot = n & (NS - 1);
        const float4* yp = reinterpret_cast<const float4*>(
            y + (((size_t)b * NS + slot) * DD + d0));
        float4 v0 = yp[0], v1 = yp[1], v2 = yp[2], v3 = yp[3];
        float4* dst = reinterpret_cast<float4*>(&sY[i][d0]);
        dst[0] = v0; dst[1] = v1; dst[2] = v2; dst[3] = v3;
    }
    __syncthreads();

    // ---- A[i][e] = dot(y_row_i, M_sel[:, e]), D=256 ----
    {
        const int i = tid >> 4;
        const int e = tid & 15;
        const int n    = sR[i];
        const int slot = n & (NS - 1);
        const float* Mp = (n < NS ? Mup : Mdn) + (size_t)slot * (DD * NE) + e;
        float acc = 0.0f;
        #pragma unroll 8
        for (int d = 0; d < DD; ++d)
            acc = fmaf(sY[i][d], Mp[(size_t)d * NE], acc);
        sA[i][e] = acc;
    }
    __syncthreads();

    if (tid >= NE) return;   // lanes 0..15 of wave 0 do the LU

    const int lane = tid;
    float a[NE];
    #pragma unroll
    for (int e = 0; e < NE; ++e) a[e] = sA[lane][e];

    unsigned used = 0u;
    float logabs = 0.0f;
    int neg = 0;
    int perm[NE];

    #pragma unroll
    for (int k = 0; k < NE; ++k) {
        // argmax |a[k]| over rows not yet used as pivots (ties -> lowest lane)
        float v = ((used >> lane) & 1u) ? -1.0f : fabsf(a[k]);
        int bi = lane;
        #pragma unroll
        for (int off = 8; off > 0; off >>= 1) {
            float ov = __shfl_xor(v, off, 16);
            int   oi = __shfl_xor(bi, off, 16);
            if (ov > v || (ov == v && oi < bi)) { v = ov; bi = oi; }
        }
        const int p = bi;                       // same in all 16 lanes
        perm[k] = p;
        const float pivval = __shfl(a[k], p, 16);
        const bool active = (((used >> lane) & 1u) == 0u) && (lane != p);
        const float m = active ? (a[k] / pivval) : 0.0f;
        #pragma unroll
        for (int e = k + 1; e < NE; ++e) {
            const float pe = __shfl(a[e], p, 16);
            a[e] = fmaf(-m, pe, a[e]);
        }
        used |= (1u << p);
        logabs += logf(fabsf(pivval));
        neg ^= (pivval < 0.0f) ? 1 : 0;
    }

    // permutation parity: inversions of the pivot sequence
    int inv = 0;
    #pragma unroll
    for (int k1 = 0; k1 < NE; ++k1) {
        #pragma unroll
        for (int k2 = k1 + 1; k2 < NE; ++k2)
            inv ^= (perm[k1] > perm[k2]) ? 1 : 0;
    }
    neg ^= inv;

    if (lane == 0) {
        float re = logabs;
        float im = neg ? 3.14159274101257324f : 0.0f;
        if (__builtin_isnan(re)) { re = -INFINITY; im = 0.0f; }
        else if (re == -INFINITY) { im = 0.0f; }   // singular: sign=0 -> +0j
        if (mode == 0) {
            out[2 * b + 0] = re;
            out[2 * b + 1] = im;
        } else {
            out[b] = re;   // harness stores real part (astype) only
        }
    }
}

extern "C" void kernel_launch(void* const* d_in, const int* in_sizes, int n_in,
                              void* d_out, int out_size, void* d_ws, size_t ws_size,
                              hipStream_t stream) {
    const float* y   = (const float*)d_in[0];
    const float* Mup = (const float*)d_in[1];
    const float* Mdn = (const float*)d_in[2];
    const int*   R   = (const int*)d_in[3];
    float* out = (float*)d_out;

    // complex64 (B,) output: if the harness exposes 2*B float32 elements,
    // write interleaved (re,im); if only B elements, write the real part.
    const int mode = (out_size >= 2 * BWALK) ? 0 : 1;

    hipLaunchKernelGGL(outputheaddet_kernel, dim3(BWALK), dim3(256), 0, stream,
                       y, Mup, Mdn, R, out, mode);
}